// Round 5
// baseline (1630.483 us; speedup 1.0000x reference)
//
#include <hip/hip_runtime.h>

// Problem constants: B=64, S=512, E=512, H=512, V=32000, T=2, L=1
// Output depends ONLY on batch sample 63 (lstm_out[-1] == last batch element).

typedef float f32x4 __attribute__((ext_vector_type(4)));
typedef unsigned long long u64;

#define NB 64   // persistent blocks for the recurrence

// LDS h-buffer swizzle: 32 chunks of 16 floats, padded to stride 20 words
// (80 B) -> float4 reads stay 16B-aligned, worst-case ~4-way bank aliasing.
#define HIDX(e) ((((e) >> 4) * 20) + ((e) & 15))

// ---------------------------------------------------------------------------
// Kernel 1: xg[t][g] = sum_e emb[sent[63][t]][e] * W_ih[g][e] + b_ih[g]+b_hh[g]
// M=512 (t), N=2048 (g), K=512. Both operands K-major (NT GEMM). (unchanged)
// ---------------------------------------------------------------------------
__global__ __launch_bounds__(256) void xg_gemm_k(
    const int* __restrict__ sent, const float* __restrict__ emb,
    const float* __restrict__ W_ih, const float* __restrict__ b_ih,
    const float* __restrict__ b_hh, float* __restrict__ xg)
{
    __shared__ float As[16][65];   // [k][m]
    __shared__ float Bs[16][65];   // [k][n]
    __shared__ int aidx[64];
    const int tid = threadIdx.x;
    const int t0 = blockIdx.x * 64;
    const int n0 = blockIdx.y * 64;
    if (tid < 64) aidx[tid] = sent[63 * 512 + t0 + tid];
    __syncthreads();

    const int kk = tid & 15;   // k within tile
    const int mm = tid >> 4;   // 0..15
    const int tx = tid & 15, ty = tid >> 4;
    float acc[4][4] = {};

    for (int kb = 0; kb < 512; kb += 16) {
        #pragma unroll
        for (int j = 0; j < 4; j++) {
            int m = mm + j * 16;
            As[kk][m] = emb[(size_t)aidx[m] * 512 + kb + kk];
            Bs[kk][m] = W_ih[(size_t)(n0 + m) * 512 + kb + kk];
        }
        __syncthreads();
        #pragma unroll
        for (int k = 0; k < 16; k++) {
            float a[4], bv[4];
            #pragma unroll
            for (int i = 0; i < 4; i++) a[i] = As[k][ty * 4 + i];
            #pragma unroll
            for (int j = 0; j < 4; j++) bv[j] = Bs[k][tx * 4 + j];
            #pragma unroll
            for (int i = 0; i < 4; i++)
                #pragma unroll
                for (int j = 0; j < 4; j++)
                    acc[i][j] += a[i] * bv[j];
        }
        __syncthreads();
    }

    #pragma unroll
    for (int i = 0; i < 4; i++) {
        int t = t0 + ty * 4 + i;
        #pragma unroll
        for (int j = 0; j < 4; j++) {
            int col = n0 + tx * 4 + j;
            xg[(size_t)t * 2048 + col] = acc[i][j] + b_ih[col] + b_hh[col];
        }
    }
}

// ---------------------------------------------------------------------------
// Kernel 2: persistent batch-1 LSTM recurrence, 512 steps, 64 blocks x 512.
// Block b owns h-indices [b*8, b*8+8). Wave rg (=tid>>6) owns h-index
// j = rg: its 4 gate rows are {q*512 + b*8 + rg}. Lane cg (=tid&63) owns
// cols [cg*8, cg*8+8) -> 32 weight floats/thread (8 VGPR quads) -- small
// enough that the allocator keeps them resident (rounds 0/2/4 proved it
// refuses at 64+ floats/thread; round 3 proved the pre-loop pin takes
// effect when the footprint is modest).
//
// Handoff (PROVEN protocol, byte-identical): h values travel as tagged
// 64-bit slots  slot = (u64)(t+1)<<32 | float_bits(h_t), relaxed
// agent-scope 8B atomic stores, readers poll the slots themselves, two
// arrays ping-pong by parity, no fences. 512 slots; thread tid polls
// slot[tid] (adjacent slots -> line-coalesced across the wave).
//
// ONE barrier per step: write hb[t&1] -> barrier -> read hb[t&1].
// Race-free: the compiler drains lgkmcnt before s_barrier, so epoch-t
// reads of hb[p] complete before any thread passes barrier(t); writes of
// hb[p] at t+2 occur after barrier(t+1) >= barrier(t).
//
// Gate tail runs INLINE on lane cg==0 of each wave (all 4 gate sums are
// in that lane after the 6-step shfl reduce): no gacc LDS round-trip, no
// second barrier, slot published ~300cy earlier.
// ---------------------------------------------------------------------------
__global__ __launch_bounds__(512, 1) void lstm_seq_k(
    const float* __restrict__ h0, const float* __restrict__ c0,
    const float* __restrict__ W_hh, const float* __restrict__ xg,
    float* __restrict__ hs,
    u64* __restrict__ sA, u64* __restrict__ sB)
{
    __shared__ float hb[2][640];   // 32 chunks * 20 words, x2 parity

    const int tid = threadIdx.x;
    const int b = blockIdx.x;
    const int cg = tid & 63;   // column lane: 8 cols each
    const int rg = tid >> 6;   // wave id = h index within block: 0..7

    // 4 gate rows of h-index rg: torch order i,f,g,o = q 0..3.
    int grow[4];
    #pragma unroll
    for (int r = 0; r < 4; ++r)
        grow[r] = r * 512 + b * 8 + rg;

    // Weight slice: 4 rows x 8 cols = 32 floats/thread, loaded ONCE and
    // pinned pre-loop (asm outputs cannot be rematerialized from memory).
    f32x4 w[4][2];
    #pragma unroll
    for (int r = 0; r < 4; ++r) {
        const float* wp = &W_hh[(size_t)grow[r] * 512 + cg * 8];
        w[r][0] = *(const f32x4*)(wp);
        w[r][1] = *(const f32x4*)(wp + 4);
    }
    asm volatile("" : "+v"(w[0][0]), "+v"(w[0][1]), "+v"(w[1][0]), "+v"(w[1][1]),
                      "+v"(w[2][0]), "+v"(w[2][1]), "+v"(w[3][0]), "+v"(w[3][1]));

    // c state: meaningful in lane cg==0 of each wave (uniform load).
    float creg = c0[63 * 512 + b * 8 + rg];

    const int hw = HIDX(tid);                       // LDS write index
    const int hr = (cg >> 1) * 20 + (cg & 1) * 8;   // LDS read base word

    for (int t = 0; t < 512; ++t) {
        const int p = t & 1;

        // Prefetch xg for this step (independent of h -> overlaps the poll).
        float xgp[4];
        if (cg == 0) {
            #pragma unroll
            for (int r = 0; r < 4; ++r)
                xgp[r] = xg[(size_t)t * 2048 + grow[r]];
        }

        if (t == 0) {
            hb[0][hw] = h0[63 * 512 + tid];
        } else {
            // Poll tagged slot of step t-1 (tag == t) in buffer (t-1)&1.
            u64* pp = &(((t - 1) & 1) ? sB : sA)[tid];
            const unsigned expt = (unsigned)t;
            u64 v;
            do {
                v = __hip_atomic_load(pp, __ATOMIC_RELAXED, __HIP_MEMORY_SCOPE_AGENT);
            } while ((unsigned)(v >> 32) != expt);
            hb[p][hw] = __uint_as_float((unsigned)v);
        }
        __syncthreads();   // the ONLY barrier per step

        // h fragment (8 cols) from LDS; 32 FMAs against resident weights.
        f32x4 hv0 = *(const f32x4*)&hb[p][hr];
        f32x4 hv1 = *(const f32x4*)&hb[p][hr + 4];

        float acc[4];
        #pragma unroll
        for (int r = 0; r < 4; ++r) {
            acc[r] = w[r][0].x * hv0.x + w[r][0].y * hv0.y
                   + w[r][0].z * hv0.z + w[r][0].w * hv0.w
                   + w[r][1].x * hv1.x + w[r][1].y * hv1.y
                   + w[r][1].z * hv1.z + w[r][1].w * hv1.w;
        }

        // Full-wave reduce (64 lanes) -> lane 0 of the wave holds row sums.
        #pragma unroll
        for (int r = 0; r < 4; ++r) {
            #pragma unroll
            for (int m = 32; m >= 1; m >>= 1)
                acc[r] += __shfl_xor(acc[r], m, 64);
        }

        // Gate tail inline on lane 0 of each wave (8 per block, parallel).
        if (cg == 0) {
            float gi = acc[0] + xgp[0];
            float gf = acc[1] + xgp[1];
            float gc = acc[2] + xgp[2];
            float go = acc[3] + xgp[3];
            float ii = 1.f / (1.f + __expf(-gi));
            float ff = 1.f / (1.f + __expf(-gf));
            float cc = 1.f - 2.f / (__expf(2.f * gc) + 1.f);   // tanh
            float oo = 1.f / (1.f + __expf(-go));
            float cn = ff * creg + ii * cc;
            creg = cn;
            float th = 1.f - 2.f / (__expf(2.f * cn) + 1.f);   // tanh
            float hval = oo * th;

            // History for the final linear (plain store; kernel-boundary
            // release makes it visible to kernel 3).
            hs[(size_t)t * 512 + b * 8 + rg] = hval;

            // Tagged slot: one 8B relaxed agent atomic store.
            u64* dst = (t & 1) ? sB : sA;
            u64 pv = ((u64)(unsigned)(t + 1) << 32) |
                     (u64)__float_as_uint(hval);
            __hip_atomic_store(&dst[b * 8 + rg], pv,
                               __ATOMIC_RELAXED, __HIP_MEMORY_SCOPE_AGENT);
        }
        // NO fence, NO flag store, NO second barrier.
    }
}

// ---------------------------------------------------------------------------
// Kernel 3: out[s][u] = hs[s] . W_lin[u] + b_lin[u], S=512, T=2. (unchanged)
// ---------------------------------------------------------------------------
__global__ __launch_bounds__(256) void final_linear_k(
    const float* __restrict__ hs, const float* __restrict__ W_lin,
    const float* __restrict__ b_lin, float* __restrict__ out)
{
    const int tid = threadIdx.x;
    const int wave = tid >> 6;
    const int lane = tid & 63;
    const int s = blockIdx.x * 4 + wave;
    const float* h = hs + (size_t)s * 512;
    float a0 = 0.f, a1 = 0.f;
    #pragma unroll
    for (int k0 = 0; k0 < 512; k0 += 64) {
        float hv = h[k0 + lane];
        a0 += hv * W_lin[k0 + lane];
        a1 += hv * W_lin[512 + k0 + lane];
    }
    #pragma unroll
    for (int m = 32; m >= 1; m >>= 1) {
        a0 += __shfl_xor(a0, m, 64);
        a1 += __shfl_xor(a1, m, 64);
    }
    if (lane == 0) {
        out[s * 2]     = a0 + b_lin[0];
        out[s * 2 + 1] = a1 + b_lin[1];
    }
}

// ---------------------------------------------------------------------------
extern "C" void kernel_launch(void* const* d_in, const int* in_sizes, int n_in,
                              void* d_out, int out_size, void* d_ws, size_t ws_size,
                              hipStream_t stream)
{
    const int*   sent  = (const int*)d_in[0];     // [64,512] int32
    const float* h0    = (const float*)d_in[1];   // [1,64,512]
    const float* c0    = (const float*)d_in[2];   // [1,64,512]
    const float* emb   = (const float*)d_in[3];   // [32000,512]
    const float* W_ih  = (const float*)d_in[4];   // [2048,512]
    const float* W_hh  = (const float*)d_in[5];   // [2048,512]
    const float* b_ih  = (const float*)d_in[6];   // [2048]
    const float* b_hh  = (const float*)d_in[7];   // [2048]
    const float* W_lin = (const float*)d_in[8];   // [2,512]
    const float* b_lin = (const float*)d_in[9];   // [2]
    float* out = (float*)d_out;                   // [512,2]

    char* ws = (char*)d_ws;
    float* xg = (float*)ws;                                   // 4 MB: [512,2048]
    float* hs = (float*)(ws + 4 * 1024 * 1024);               // 1 MB: [512,512]
    u64* sA = (u64*)(ws + 5 * 1024 * 1024);                   // 4 KB
    u64* sB = (u64*)(ws + 5 * 1024 * 1024 + 4096);            // 4 KB

    // Clear slot tags (0 != any expected tag 1..512).
    hipMemsetAsync(sA, 0, 2 * 4096, stream);

    dim3 g1(8, 32);
    xg_gemm_k<<<g1, 256, 0, stream>>>(sent, emb, W_ih, b_ih, b_hh, xg);
    lstm_seq_k<<<NB, 512, 0, stream>>>(h0, c0, W_hh, xg, hs, sA, sB);
    final_linear_k<<<128, 256, 0, stream>>>(hs, W_lin, b_lin, out);
}